// Round 2
// 1234.444 us; speedup vs baseline: 1.0482x; 1.0482x over previous
//
#include <hip/hip_runtime.h>

// Problem constants
#define B_   2048
#define T_   32
#define DIN_ 1024
#define DH_  64
#define H_   512
#define KL_  576   // DH_ + H_
#define AO_  64

typedef unsigned short u16;
typedef unsigned int   u32;
typedef __attribute__((ext_vector_type(8))) short          bf16x8;
typedef __attribute__((ext_vector_type(8))) unsigned short u16x8;
typedef __attribute__((ext_vector_type(4))) float          f32x4;

__device__ __forceinline__ u16 f2bf(float f) {
  u32 u = __builtin_bit_cast(u32, f);
  u = (u + 0x7FFFu + ((u >> 16) & 1u)) >> 16;
  return (u16)u;
}
__device__ __forceinline__ float bf2f(u16 s) {
  return __builtin_bit_cast(float, (u32)s << 16);
}
__device__ __forceinline__ float sigm(float x) { return 1.f / (1.f + __expf(-x)); }
// tanh via exp, saturates correctly at +/-inf (no NaN)
__device__ __forceinline__ float tanh_(float x) { return 1.f - 2.f / (__expf(2.f * x) + 1.f); }

// async global->LDS, 16B/lane; LDS dest = wave-uniform base + lane*16
__device__ __forceinline__ void gl_lds16(const void* g, void* l) {
  __builtin_amdgcn_global_load_lds((const __attribute__((address_space(1))) u32*)g,
                                   (__attribute__((address_space(3))) u32*)l, 16, 0, 0);
}

// dst[n][k] = bf16(src[k][n]);  K,N multiples of 32
__global__ __launch_bounds__(256) void k_transpose(const float* __restrict__ src,
                                                   u16* __restrict__ dst, int K, int N) {
  __shared__ float t[32][33];
  const int n0 = blockIdx.x * 32, k0 = blockIdx.y * 32;
  const int a = threadIdx.x >> 5, b = threadIdx.x & 31;
#pragma unroll
  for (int i = 0; i < 4; ++i)
    t[a + 8 * i][b] = src[(size_t)(k0 + a + 8 * i) * N + n0 + b];
  __syncthreads();
#pragma unroll
  for (int i = 0; i < 4; ++i)
    dst[(size_t)(n0 + a + 8 * i) * K + k0 + b] = f2bf(t[b][a + 8 * i]);
}

// gW[n] = sum_k g[k]*W[k][n];  bW[n] = sum_k b[k]*W[k][n]   (W is [1024][64])
__global__ void k_gw(const float* __restrict__ W, const float* __restrict__ g,
                     const float* __restrict__ b, float* __restrict__ gW,
                     float* __restrict__ bW) {
  const int n = threadIdx.x;
  float sg = 0.f, sb = 0.f;
  for (int k = 0; k < DIN_; ++k) {
    const float w = W[k * DH_ + n];
    sg += g[k] * w; sb += b[k] * w;
  }
  gW[n] = sg; bW[n] = sb;
}

// Front end: LN1 (folded) -> dense -> LN2 -> relu -> bf16 x [B*T, 64]
__global__ __launch_bounds__(256) void k_front(
    const float* __restrict__ ud, const float* __restrict__ g1,
    const u16* __restrict__ Wdt, const float* __restrict__ gW,
    const float* __restrict__ bW, const float* __restrict__ bd,
    const float* __restrict__ g2, const float* __restrict__ b2,
    u16* __restrict__ xout) {
  __shared__ u16 lA[64 * 32];
  __shared__ u16 lB[64 * 32];
  __shared__ float smu[64], srs[64];
  const int tid = threadIdx.x, wave = tid >> 6, lane = tid & 63;
  const int m0 = blockIdx.x * 64;
  const int arow = tid >> 2, ach = tid & 3;
  const float* __restrict__ udp = ud + (size_t)(m0 + arow) * DIN_ + ach * 8;
  const float* __restrict__ g1p = g1 + ach * 8;
  const int cB = wave * 16 + (lane >> 2);
  const u16* __restrict__ wdp = Wdt + (size_t)cB * DIN_ + (lane & 3) * 8;
  u16* const lBb = &lB[wave * 512];
  u16x8* const lAp = (u16x8*)&lA[arow * 32 + ach * 8];
  const int quad = lane >> 4, col = lane & 15;

  float sx = 0.f, sxx = 0.f;
  f32x4 acc[4] = {};
  for (int kt = 0; kt < 32; ++kt) {
    const int k0 = kt * 32;
    __syncthreads();
    const float4 v0 = *(const float4*)(udp + k0);
    const float4 v1 = *(const float4*)(udp + k0 + 4);
    const float4 ga = *(const float4*)(g1p + k0);
    const float4 gb = *(const float4*)(g1p + k0 + 4);
    sx  += v0.x + v0.y + v0.z + v0.w + v1.x + v1.y + v1.z + v1.w;
    sxx += v0.x * v0.x + v0.y * v0.y + v0.z * v0.z + v0.w * v0.w
         + v1.x * v1.x + v1.y * v1.y + v1.z * v1.z + v1.w * v1.w;
    u16x8 pk;
    pk[0] = f2bf(v0.x * ga.x); pk[1] = f2bf(v0.y * ga.y);
    pk[2] = f2bf(v0.z * ga.z); pk[3] = f2bf(v0.w * ga.w);
    pk[4] = f2bf(v1.x * gb.x); pk[5] = f2bf(v1.y * gb.y);
    pk[6] = f2bf(v1.z * gb.z); pk[7] = f2bf(v1.w * gb.w);
    *lAp = pk;
    gl_lds16(wdp + k0, lBb);
    __syncthreads();
    const bf16x8 af = *(const bf16x8*)&lA[(wave * 16 + col) * 32 + quad * 8];
#pragma unroll
    for (int nt = 0; nt < 4; ++nt) {
      const bf16x8 bfr = *(const bf16x8*)&lB[(nt * 16 + col) * 32 + quad * 8];
      acc[nt] = __builtin_amdgcn_mfma_f32_16x16x32_bf16(af, bfr, acc[nt], 0, 0, 0);
    }
  }
  // per-row LN1 stats: reduce the 4 staging lanes of each row
  sx  += __shfl_xor(sx, 1);  sx  += __shfl_xor(sx, 2);
  sxx += __shfl_xor(sxx, 1); sxx += __shfl_xor(sxx, 2);
  if ((lane & 3) == 0) {
    const float mu = sx * (1.f / DIN_);
    const float var = sxx * (1.f / DIN_) - mu * mu;
    smu[arow] = mu;
    srs[arow] = rsqrtf(var + 1e-12f);
  }
  __syncthreads();
  float gwv[4], bwv[4], g2v[4], b2v[4];
#pragma unroll
  for (int nt = 0; nt < 4; ++nt) {
    const int n = nt * 16 + col;
    gwv[nt] = gW[n]; bwv[nt] = bW[n] + bd[n]; g2v[nt] = g2[n]; b2v[nt] = b2[n];
  }
#pragma unroll
  for (int r = 0; r < 4; ++r) {
    const int rl = wave * 16 + quad * 4 + r;
    const float mu = smu[rl], rs = srs[rl];
    float y[4]; float s1 = 0.f, s2 = 0.f;
#pragma unroll
    for (int nt = 0; nt < 4; ++nt) {
      y[nt] = rs * (acc[nt][r] - mu * gwv[nt]) + bwv[nt];
      s1 += y[nt]; s2 += y[nt] * y[nt];
    }
    s1 += __shfl_xor(s1, 1); s1 += __shfl_xor(s1, 2);
    s1 += __shfl_xor(s1, 4); s1 += __shfl_xor(s1, 8);
    s2 += __shfl_xor(s2, 1); s2 += __shfl_xor(s2, 2);
    s2 += __shfl_xor(s2, 4); s2 += __shfl_xor(s2, 8);
    const float mu2 = s1 * (1.f / 64.f);
    const float rs2 = rsqrtf(s2 * (1.f / 64.f) - mu2 * mu2 + 1e-12f);
    const size_t R = m0 + rl;
#pragma unroll
    for (int nt = 0; nt < 4; ++nt) {
      const float v = fmaxf((y[nt] - mu2) * rs2 * g2v[nt] + b2v[nt], 0.f);
      xout[R * 64 + nt * 16 + col] = f2bf(v);
    }
  }
}

// One LSTM timestep, both directions (blockIdx.z). GEMM [2048 x (4x32)] x K=576
// with gate-interleaved columns so the cell update is a register-local epilogue.
// K-loop: BK=64, double-buffered LDS, issue-early prefetch (T3 2-phase),
// XOR-swizzled LDS layout (pre-swizzled global source; swizzled ds_read) to
// kill the 8-way bank conflict of the row-major [row][BK] tile.
__global__ __launch_bounds__(256) void k_step(
    const int s, const u16* __restrict__ x, const u16* __restrict__ Wt,
    const float* __restrict__ bfw, const float* __restrict__ bbw,
    const int* __restrict__ au, u16* __restrict__ hstate,
    float* __restrict__ cstate, u16* __restrict__ hout) {
  __shared__ u16 lA[2][128 * 64];   // [dbuf][row][64k], rows swizzled by ((row&7)<<4) bytes
  __shared__ u16 lB[2][128 * 64];
  const int tid = threadIdx.x, wave = tid >> 6, lane = tid & 63;
  const int dir = blockIdx.z;
  const int m0 = blockIdx.x * 128;
  const int u0 = blockIdx.y * 32;
  const int rb = s & 1, wb = rb ^ 1;  // h-state ping-pong
  const u16* __restrict__ Wtd = Wt + (size_t)dir * 2048 * KL_;
  const float* __restrict__ bias = dir ? bbw : bfw;

  // staging: each wave owns chunks ch0,ch1 (16 rows each); 2 gl_lds per chunk
  // lane -> (row = lane>>3 within 8-row half, 16B slot (lane&7)); the global
  // k-offset is pre-swizzled so data lands XOR-swizzled in linear LDS.
  const int lrow = lane >> 3;
  const int kk = ((lane & 7) ^ lrow) * 8;   // swizzled k offset, elems
  const int ch0 = 2 * wave, ch1 = ch0 + 1;

  const u16* gx[4]; const u16* gh[2]; const u16* gB[2];
#pragma unroll
  for (int i = 0; i < 2; ++i) {
    const int ch = ch0 + i;
#pragma unroll
    for (int h = 0; h < 2; ++h) {
      const int b = m0 + ch * 16 + h * 8 + lrow;
      const int aub = au[b];
      const int tin = (dir == 0) ? s : ((s < aub) ? (aub - 1 - s) : s);
      gx[i * 2 + h] = x + ((size_t)b * T_ + tin) * DH_ + kk;
    }
    const int b0 = m0 + ch * 16 + lrow;
    gh[i] = hstate + (((size_t)dir * 2 + rb) * B_ + b0) * H_ + kk;
    // B columns: tile col c -> gate=(c>>4)&3, u = u0 + ((c>>6)<<4) + (c&15)
    const int n = 512 * (ch & 3) + u0 + ((ch >> 2) << 4) + lrow;
    gB[i] = Wtd + (size_t)n * KL_ + kk;
  }

  // prologue: stage K-tile 0 (x part) into buffer 0
  gl_lds16(gx[0], &lA[0][ch0 * 1024]);
  gl_lds16(gx[1], &lA[0][ch0 * 1024 + 512]);
  gl_lds16(gx[2], &lA[0][ch1 * 1024]);
  gl_lds16(gx[3], &lA[0][ch1 * 1024 + 512]);
  gl_lds16(gB[0],           &lB[0][ch0 * 1024]);
  gl_lds16(gB[0] + 8 * KL_, &lB[0][ch0 * 1024 + 512]);
  gl_lds16(gB[1],           &lB[0][ch1 * 1024]);
  gl_lds16(gB[1] + 8 * KL_, &lB[0][ch1 * 1024 + 512]);
  __syncthreads();   // drains vmcnt(0): tile 0 resident

  f32x4 acc[4][4] = {};
  const int wm = wave >> 1, wn = wave & 1, quad = lane >> 4, col = lane & 15;
  const int swz = (col & 7) << 4;   // byte XOR for reads (row&7 == col&7)

  int cur = 0;
  for (int kt = 0; kt < 9; ++kt) {
    // issue prefetch of tile kt+1 into the other buffer BEFORE computing kt;
    // the trailing __syncthreads() (vmcnt(0) drain) makes it resident by kt+1.
    if (kt < 8) {
      const int nb = cur ^ 1;
      const int kh = kt * 64;            // h k-offset for tile kt+1: (kt+1)*64-64
      gl_lds16(gh[0] + kh,          &lA[nb][ch0 * 1024]);
      gl_lds16(gh[0] + kh + 8 * H_, &lA[nb][ch0 * 1024 + 512]);
      gl_lds16(gh[1] + kh,          &lA[nb][ch1 * 1024]);
      gl_lds16(gh[1] + kh + 8 * H_, &lA[nb][ch1 * 1024 + 512]);
      gl_lds16(gB[0] + kh + 64,            &lB[nb][ch0 * 1024]);
      gl_lds16(gB[0] + kh + 64 + 8 * KL_,  &lB[nb][ch0 * 1024 + 512]);
      gl_lds16(gB[1] + kh + 64,            &lB[nb][ch1 * 1024]);
      gl_lds16(gB[1] + kh + 64 + 8 * KL_,  &lB[nb][ch1 * 1024 + 512]);
    }
    const char* la = (const char*)&lA[cur][0];
    const char* lb = (const char*)&lB[cur][0];
#pragma unroll
    for (int ks = 0; ks < 2; ++ks) {
      const int bko = (ks * 64 + quad * 16) ^ swz;   // swizzled byte offset in row
      bf16x8 bfrag[4];
#pragma unroll
      for (int nt = 0; nt < 4; ++nt)
        bfrag[nt] = *(const bf16x8*)(lb + (wn * 64 + nt * 16 + col) * 128 + bko);
#pragma unroll
      for (int mt = 0; mt < 4; ++mt) {
        const bf16x8 afrag = *(const bf16x8*)(la + (wm * 64 + mt * 16 + col) * 128 + bko);
#pragma unroll
        for (int nt = 0; nt < 4; ++nt)
          acc[mt][nt] = __builtin_amdgcn_mfma_f32_16x16x32_bf16(afrag, bfrag[nt], acc[mt][nt], 0, 0, 0);
      }
    }
    __syncthreads();   // one barrier per K-tile: everyone done reading cur,
                       // everyone's prefetch into cur^1 drained (vmcnt 0)
    cur ^= 1;
  }

  const int u = u0 + wn * 16 + col;
  const float bi = bias[u], bj = bias[512 + u], bff = bias[1024 + u], bo = bias[1536 + u];
#pragma unroll
  for (int mt = 0; mt < 4; ++mt) {
#pragma unroll
    for (int r = 0; r < 4; ++r) {
      const int brow = m0 + wm * 64 + mt * 16 + quad * 4 + r;
      const size_t ci = ((size_t)dir * B_ + brow) * H_ + u;
      const float zi = acc[mt][0][r] + bi;
      const float zj = acc[mt][1][r] + bj;
      const float zf = acc[mt][2][r] + bff;
      const float zo = acc[mt][3][r] + bo;
      const float cn = cstate[ci] * sigm(zf + 1.f) + sigm(zi) * tanh_(zj);
      const float hn = tanh_(cn) * sigm(zo);
      cstate[ci] = cn;
      hstate[(((size_t)dir * 2 + wb) * B_ + brow) * H_ + u] = f2bf(hn);
      const int aub = au[brow];
      const bool valid = (s < aub);
      const int pos = (dir == 0) ? s : (valid ? (aub - 1 - s) : s);
      const float val = valid ? hn : 0.f;
      hout[((size_t)brow * T_ + pos) * 1024 + (dir ? 512 : 0) + u] = f2bf(val);
    }
  }
}

// LN3 stats per batch element over [T,1024]
__global__ __launch_bounds__(256) void k_ln3stats(const u16* __restrict__ hout,
                                                  float* __restrict__ st) {
  const int b = blockIdx.x, tid = threadIdx.x;
  const uint4* __restrict__ p = (const uint4*)(hout + (size_t)b * T_ * 1024);
  float sx = 0.f, sxx = 0.f;
  for (int j = tid; j < 4096; j += 256) {
    const uint4 q = p[j];
    const u32 w[4] = {q.x, q.y, q.z, q.w};
#pragma unroll
    for (int e = 0; e < 4; ++e) {
      const float a = bf2f((u16)(w[e] & 0xffff));
      const float c = bf2f((u16)(w[e] >> 16));
      sx += a + c; sxx += a * a + c * c;
    }
  }
#pragma unroll
  for (int m = 1; m < 64; m <<= 1) { sx += __shfl_xor(sx, m); sxx += __shfl_xor(sxx, m); }
  __shared__ float rs_[4], rq_[4];
  if ((tid & 63) == 0) { rs_[tid >> 6] = sx; rq_[tid >> 6] = sxx; }
  __syncthreads();
  if (tid == 0) {
    const float a = rs_[0] + rs_[1] + rs_[2] + rs_[3];
    const float c = rq_[0] + rq_[1] + rq_[2] + rq_[3];
    const float mu = a / 32768.f;
    const float var = c / 32768.f - mu * mu;
    st[b * 2] = mu; st[b * 2 + 1] = rsqrtf(var + 1e-12f);
  }
}

// LN3-apply + relu -> conv (GEMM vs Wct) -> tanh -> out fp32
__global__ __launch_bounds__(256) void k_final(
    const u16* __restrict__ hin, const float* __restrict__ st,
    const float* __restrict__ g3, const float* __restrict__ b3,
    const u16* __restrict__ Wct, const float* __restrict__ bc,
    float* __restrict__ out) {
  __shared__ u16 lA[64 * 32];
  __shared__ u16 lB[64 * 32];
  const int tid = threadIdx.x, wave = tid >> 6, lane = tid & 63;
  const int m0 = blockIdx.x * 64;
  const int arow = tid >> 2, ach = tid & 3;
  const size_t R = m0 + arow;
  const float mu = st[(R >> 5) * 2], rs = st[(R >> 5) * 2 + 1];
  const u16* __restrict__ hp = hin + R * 1024 + ach * 8;
  const float* __restrict__ g3p = g3 + ach * 8;
  const float* __restrict__ b3p = b3 + ach * 8;
  const int cB = wave * 16 + (lane >> 2);
  const u16* __restrict__ wcp = Wct + (size_t)cB * DIN_ + (lane & 3) * 8;
  u16* const lBb = &lB[wave * 512];
  u16x8* const lAp = (u16x8*)&lA[arow * 32 + ach * 8];
  const int quad = lane >> 4, col = lane & 15;
  f32x4 acc[4] = {};
  for (int kt = 0; kt < 32; ++kt) {
    const int k0 = kt * 32;
    __syncthreads();
    const uint4 q = *(const uint4*)(hp + k0);
    const float4 ga = *(const float4*)(g3p + k0);
    const float4 gb = *(const float4*)(g3p + k0 + 4);
    const float4 ba = *(const float4*)(b3p + k0);
    const float4 bb = *(const float4*)(b3p + k0 + 4);
    float hv[8];
    hv[0] = bf2f((u16)(q.x & 0xffff)); hv[1] = bf2f((u16)(q.x >> 16));
    hv[2] = bf2f((u16)(q.y & 0xffff)); hv[3] = bf2f((u16)(q.y >> 16));
    hv[4] = bf2f((u16)(q.z & 0xffff)); hv[5] = bf2f((u16)(q.z >> 16));
    hv[6] = bf2f((u16)(q.w & 0xffff)); hv[7] = bf2f((u16)(q.w >> 16));
    u16x8 pk;
    pk[0] = f2bf(fmaxf((hv[0] - mu) * rs * ga.x + ba.x, 0.f));
    pk[1] = f2bf(fmaxf((hv[1] - mu) * rs * ga.y + ba.y, 0.f));
    pk[2] = f2bf(fmaxf((hv[2] - mu) * rs * ga.z + ba.z, 0.f));
    pk[3] = f2bf(fmaxf((hv[3] - mu) * rs * ga.w + ba.w, 0.f));
    pk[4] = f2bf(fmaxf((hv[4] - mu) * rs * gb.x + bb.x, 0.f));
    pk[5] = f2bf(fmaxf((hv[5] - mu) * rs * gb.y + bb.y, 0.f));
    pk[6] = f2bf(fmaxf((hv[6] - mu) * rs * gb.z + bb.z, 0.f));
    pk[7] = f2bf(fmaxf((hv[7] - mu) * rs * gb.w + bb.w, 0.f));
    *lAp = pk;
    gl_lds16(wcp + k0, lBb);
    __syncthreads();
    const bf16x8 af = *(const bf16x8*)&lA[(wave * 16 + col) * 32 + quad * 8];
#pragma unroll
    for (int nt = 0; nt < 4; ++nt) {
      const bf16x8 bfr = *(const bf16x8*)&lB[(nt * 16 + col) * 32 + quad * 8];
      acc[nt] = __builtin_amdgcn_mfma_f32_16x16x32_bf16(af, bfr, acc[nt], 0, 0, 0);
    }
  }
  float bcv[4];
#pragma unroll
  for (int nt = 0; nt < 4; ++nt) bcv[nt] = bc[nt * 16 + col];
#pragma unroll
  for (int r = 0; r < 4; ++r) {
    const size_t R2 = m0 + wave * 16 + quad * 4 + r;
#pragma unroll
    for (int nt = 0; nt < 4; ++nt)
      out[R2 * 64 + nt * 16 + col] = tanh_(acc[nt][r] + bcv[nt]);
  }
}

extern "C" void kernel_launch(void* const* d_in, const int* in_sizes, int n_in,
                              void* d_out, int out_size, void* d_ws, size_t ws_size,
                              hipStream_t stream) {
  (void)in_sizes; (void)n_in; (void)out_size; (void)ws_size;
  const float* ud  = (const float*)d_in[0];
  const int*   au  = (const int*)d_in[2];
  const float* g1  = (const float*)d_in[4];
  const float* b1  = (const float*)d_in[5];
  const float* Wd  = (const float*)d_in[6];
  const float* bd  = (const float*)d_in[7];
  const float* g2  = (const float*)d_in[8];
  const float* b2  = (const float*)d_in[9];
  const float* Wfw = (const float*)d_in[10];
  const float* bfw = (const float*)d_in[11];
  const float* Wbw = (const float*)d_in[12];
  const float* bbw = (const float*)d_in[13];
  const float* g3  = (const float*)d_in[14];
  const float* b3  = (const float*)d_in[15];
  const float* Wc  = (const float*)d_in[16];
  const float* bc  = (const float*)d_in[17];

  char* p = (char*)d_ws;
  size_t off = 0;
  auto take = [&](size_t bytes) {
    char* r = p + off;
    off = (off + bytes + 255) & ~(size_t)255;
    return r;
  };
  u16*   xbf    = (u16*)  take((size_t)B_ * T_ * DH_ * 2);        // 8 MB
  u16*   Wt     = (u16*)  take((size_t)2 * 2048 * KL_ * 2);       // 4.5 MB [dir][n][k]
  u16*   Wdt    = (u16*)  take((size_t)DH_ * DIN_ * 2);
  u16*   Wct    = (u16*)  take((size_t)AO_ * DIN_ * 2);
  float* gWv    = (float*)take(64 * 4);
  float* bWv    = (float*)take(64 * 4);
  u16*   hstate = (u16*)  take((size_t)2 * 2 * B_ * H_ * 2);      // 8 MB [dir][pp][B][H]
  float* cstate = (float*)take((size_t)2 * B_ * H_ * 4);          // 8 MB
  u16*   hout   = (u16*)  take((size_t)B_ * T_ * 1024 * 2);      // 128 MB
  float* st3    = (float*)take((size_t)B_ * 2 * 4);

  // zero LSTM state (ws is poisoned before every timed call)
  hipMemsetAsync(hstate, 0, (size_t)2 * 2 * B_ * H_ * 2 + (size_t)2 * B_ * H_ * 4, stream);

  k_transpose<<<dim3(64, 18), 256, 0, stream>>>(Wfw, Wt,              KL_, 2048);
  k_transpose<<<dim3(64, 18), 256, 0, stream>>>(Wbw, Wt + 2048 * KL_, KL_, 2048);
  k_transpose<<<dim3(2, 32),  256, 0, stream>>>(Wd,  Wdt, DIN_, DH_);
  k_transpose<<<dim3(2, 32),  256, 0, stream>>>(Wc,  Wct, DIN_, AO_);
  k_gw<<<1, 64, 0, stream>>>(Wd, g1, b1, gWv, bWv);
  k_front<<<B_ * T_ / 64, 256, 0, stream>>>(ud, g1, Wdt, gWv, bWv, bd, g2, b2, xbf);
  for (int s = 0; s < T_; ++s)
    k_step<<<dim3(16, 16, 2), 256, 0, stream>>>(s, xbf, Wt, bfw, bbw, au, hstate, cstate, hout);
  k_ln3stats<<<B_, 256, 0, stream>>>(hout, st3);
  k_final<<<B_ * T_ / 64, 256, 0, stream>>>(hout, st3, g3, b3, Wct, bc, (float*)d_out);
}